// Round 1
// baseline (445.693 us; speedup 1.0000x reference)
//
#include <hip/hip_runtime.h>
#include <math.h>

// Problem constants (from reference)
constexpr int cS  = 16;   // sequence
constexpr int cB  = 8;    // batch
constexpr int cNC = 5;    // classes
constexpr int cD  = 256;  // hidden
constexpr int cH  = 16;   // heads
constexpr int cP  = 16;   // patches
constexpr int cPD = 49;   // patch dim
constexpr int cDFT = 128; // channel-mixer hidden
constexpr int cEP  = 64;  // token-mixer hidden (EF*P)
#define LEPS 1e-5f

__device__ __forceinline__ float gelu_t(float x) {
  // jax.nn.gelu approximate=True (tanh)
  float x3 = x * x * x;
  return 0.5f * x * (1.0f + tanhf(0.7978845608028654f * (x + 0.044715f * x3)));
}
__device__ __forceinline__ float sigm(float x) { return 1.0f / (1.0f + __expf(-x)); }

// ---------------- embed: patchify + one-hot concat + linear ----------------
// grid = S*B*P blocks, 256 threads (one per output d)
__global__ __launch_bounds__(256) void k_embed(const float* __restrict__ x,
                                               const int* __restrict__ fb,
                                               const float* __restrict__ inW,
                                               const float* __restrict__ inb,
                                               float* __restrict__ h) {
  const int blk = blockIdx.x;
  const int p  = blk & 15;        // patch
  const int sb = blk >> 4;        // s*B + b
  const int ph = p >> 2, pw = p & 3;
  __shared__ float sx[cPD];
  const int t = threadIdx.x;
  if (t < cPD) {
    const int p1 = t / 7, p2 = t % 7;
    sx[t] = x[(size_t)sb * 784 + (ph * 7 + p1) * 28 + (pw * 7 + p2)];
  }
  __syncthreads();
  const int cls = fb[sb];
  float acc = inb[t] + inW[(size_t)(cPD + cls) * cD + t];  // one-hot row
#pragma unroll
  for (int j = 0; j < cPD; ++j) acc += sx[j] * inW[(size_t)j * cD + t];
  h[((size_t)sb * cP + p) * cD + t] = acc;
}

// ---------------- token SRWM: features = patch axis (16), batch = B*D ------
// grid = 128 blocks; block handles 16 instances (d0..d0+15 of one b).
// thread (li, r): instance li, row r. State rows in registers.
__global__ __launch_bounds__(256) void k_tok_srwm(
    float* __restrict__ h, const float* __restrict__ Wy0, const float* __restrict__ Wq0,
    const float* __restrict__ Wk0, const float* __restrict__ wb0,
    const float* __restrict__ lng, const float* __restrict__ lnb) {
  const int t  = threadIdx.x;
  const int li = t >> 4;          // local instance (d-lane)
  const int r  = t & 15;          // row
  const int b  = blockIdx.x >> 4;
  const int d0 = (blockIdx.x & 15) << 4;
  float wy[16], wq[16], wk[16], wbr[16];
#pragma unroll
  for (int j = 0; j < 16; ++j) {
    wy[j]  = Wy0[r * 16 + j];
    wq[j]  = Wq0[r * 16 + j];
    wk[j]  = Wk0[r * 16 + j];
    wbr[j] = wb0[(r & 3) * 16 + j];
  }
  __shared__ float xs[16][16];   // [d-lane][row]
  __shared__ float qv[16][16], kv[16][16], qsv[16][16], ksv[16][16], ayv[16][16], yv[16][16];
  __shared__ float bts[16][4];
  const float gg = lng[r], bb = lnb[r];
  const int lr = t >> 4;   // cooperative load: row
  const int ld = t & 15;   // cooperative load: d-lane
  for (int s = 0; s < cS; ++s) {
    const size_t rowbase = ((size_t)(s * cB + b) * cP) * cD + d0;
    xs[ld][lr] = h[rowbase + (size_t)lr * cD + ld];     // coalesced 16-float runs
    __syncthreads();
    float y = 0.f, q = 0.f, k = 0.f, bt = 0.f;
#pragma unroll
    for (int j = 0; j < 16; ++j) {
      const float xv = xs[li][j];
      y += wy[j] * xv; q += wq[j] * xv; k += wk[j] * xv; bt += wbr[j] * xv;
    }
    yv[li][r] = y; qv[li][r] = q; kv[li][r] = k;
    if (r < 4) bts[li][r] = sigm(bt);
    __syncthreads();
    float mq = -1e30f, mk = -1e30f;
#pragma unroll
    for (int j = 0; j < 16; ++j) { mq = fmaxf(mq, qv[li][j]); mk = fmaxf(mk, kv[li][j]); }
    float sq = 0.f, sk = 0.f;
#pragma unroll
    for (int j = 0; j < 16; ++j) { sq += __expf(qv[li][j] - mq); sk += __expf(kv[li][j] - mk); }
    const float qsr = __expf(q - mq) / sq;
    const float ksr = __expf(k - mk) / sk;
    qsv[li][r] = qsr; ksv[li][r] = ksr;
    __syncthreads();
    float ay = 0.f, vyk = 0.f, vqk = 0.f, vkk = 0.f, vqq = 0.f, vkq = 0.f, vbk = 0.f, vbq = 0.f;
#pragma unroll
    for (int j = 0; j < 16; ++j) {
      const float qj = qsv[li][j], kj = ksv[li][j];
      ay  += wy[j]  * qj; vyk += wy[j]  * kj;
      vqq += wq[j]  * qj; vqk += wq[j]  * kj;
      vkq += wk[j]  * qj; vkk += wk[j]  * kj;
      vbq += wbr[j] * qj; vbk += wbr[j] * kj;
    }
    ayv[li][r] = ay;
    __syncthreads();
    float ma = -1e30f;
#pragma unroll
    for (int j = 0; j < 16; ++j) ma = fmaxf(ma, ayv[li][j]);
    float sa = 0.f;
#pragma unroll
    for (int j = 0; j < 16; ++j) sa += __expf(ayv[li][j] - ma);
    const float vyq = __expf(ay - ma) / sa;
    const float b0 = bts[li][0], b1v = bts[li][1], b2v = bts[li][2], b3v = bts[li][3];
    const float cy = b0 * (vyq - vyk), cq = b1v * (vqq - vqk);
    const float ck = b2v * (vkq - vkk), cb = b3v * (vbq - vbk);
#pragma unroll
    for (int j = 0; j < 16; ++j) {
      const float kj = ksv[li][j];
      wy[j] += cy * kj; wq[j] += cq * kj; wk[j] += ck * kj; wbr[j] += cb * kj;
    }
    // LN over the 16-dim y (per instance)
    float m = 0.f;
#pragma unroll
    for (int j = 0; j < 16; ++j) m += yv[li][j];
    m *= 0.0625f;
    float var = 0.f;
#pragma unroll
    for (int j = 0; j < 16; ++j) { const float dv = yv[li][j] - m; var += dv * dv; }
    var *= 0.0625f;
    const float outv = (y - m) * rsqrtf(var + LEPS) * gg + bb;
    qv[li][r] = outv;          // reuse qv as output staging (reads done pre-sync)
    __syncthreads();
    h[rowbase + (size_t)lr * cD + ld] = qv[ld][lr];     // coalesced store
  }
}

// ---------------- token mixer: LN(D) then FFN over patch axis --------------
// grid = S*B blocks, 256 threads (one per d)
__global__ __launch_bounds__(256) void k_tok_mixer(
    float* __restrict__ h, const float* __restrict__ g, const float* __restrict__ bta,
    const float* __restrict__ W1, const float* __restrict__ b1,
    const float* __restrict__ W2, const float* __restrict__ b2) {
  const int sb = blockIdx.x;
  const int t = threadIdx.x;
  __shared__ float tile[16][256];
  __shared__ float W1s[16 * 64], W2s[64 * 16];
  __shared__ float mean_[16], rstd_[16];
  __shared__ float red[16][17], red2[16][17];
  const size_t base = (size_t)sb * cP * cD;
#pragma unroll
  for (int p = 0; p < 16; ++p) tile[p][t] = h[base + p * 256 + t];
  W1s[t] = W1[t]; W1s[t + 256] = W1[t + 256]; W1s[t + 512] = W1[t + 512]; W1s[t + 768] = W1[t + 768];
  W2s[t] = W2[t]; W2s[t + 256] = W2[t + 256]; W2s[t + 512] = W2[t + 512]; W2s[t + 768] = W2[t + 768];
  __syncthreads();
  // LN stats: 16 threads per row p
  const int p = t >> 4, l = t & 15;
  float ps = 0.f, ps2 = 0.f;
#pragma unroll
  for (int k = 0; k < 16; ++k) { const float v = tile[p][l + 16 * k]; ps += v; ps2 += v * v; }
  red[p][l] = ps; red2[p][l] = ps2;
  __syncthreads();
  if (t < 16) {
    float sm = 0.f, s2 = 0.f;
#pragma unroll
    for (int k = 0; k < 16; ++k) { sm += red[t][k]; s2 += red2[t][k]; }
    const float m = sm * (1.f / 256.f);
    mean_[t] = m;
    rstd_[t] = rsqrtf(s2 * (1.f / 256.f) - m * m + LEPS);
  }
  __syncthreads();
  const float gd = g[t], bd = bta[t];
  float v[16], out[16];
#pragma unroll
  for (int pp = 0; pp < 16; ++pp) {
    v[pp] = (tile[pp][t] - mean_[pp]) * rstd_[pp] * gd + bd;
    out[pp] = b2[pp];
  }
  for (int e = 0; e < cEP; ++e) {
    float acc = b1[e];
#pragma unroll
    for (int pp = 0; pp < 16; ++pp) acc += v[pp] * W1s[pp * 64 + e];
    const float ge = gelu_t(acc);
#pragma unroll
    for (int pp = 0; pp < 16; ++pp) out[pp] += ge * W2s[e * 16 + pp];
  }
#pragma unroll
  for (int pp = 0; pp < 16; ++pp) h[base + pp * 256 + t] = tile[pp][t] + out[pp];
}

// ---------------- channel SRWM: 16 heads of dh=16, batch = B*P -------------
// grid = B*P = 128 blocks; thread (hh, r). LN couples all heads (dim 256).
__global__ __launch_bounds__(256) void k_ch_srwm(
    float* __restrict__ h, const float* __restrict__ Wy0, const float* __restrict__ Wq0,
    const float* __restrict__ Wk0, const float* __restrict__ wb0,
    const float* __restrict__ lng, const float* __restrict__ lnb) {
  const int t = threadIdx.x;
  const int hh = t >> 4, r = t & 15;
  const int bp = blockIdx.x;
  float wy[16], wq[16], wk[16], wbr[16];
#pragma unroll
  for (int j = 0; j < 16; ++j) {
    wy[j]  = Wy0[(hh * 16 + r) * 16 + j];
    wq[j]  = Wq0[(hh * 16 + r) * 16 + j];
    wk[j]  = Wk0[(hh * 16 + r) * 16 + j];
    wbr[j] = wb0[(hh * 4 + (r & 3)) * 16 + j];
  }
  __shared__ float xs[256];
  __shared__ float qv[16][16], kv[16][16], qsv[16][16], ksv[16][16], ayv[16][16];
  __shared__ float bts[16][4];
  __shared__ float sum4[4], sq4[4];
  const float gg = lng[t], bb = lnb[t];
  for (int s = 0; s < cS; ++s) {
    const size_t base = (size_t)(s * cB * cP + bp) * cD;
    xs[t] = h[base + t];
    __syncthreads();
    float y = 0.f, q = 0.f, k = 0.f, bt = 0.f;
#pragma unroll
    for (int j = 0; j < 16; ++j) {
      const float xv = xs[hh * 16 + j];
      y += wy[j] * xv; q += wq[j] * xv; k += wk[j] * xv; bt += wbr[j] * xv;
    }
    qv[hh][r] = q; kv[hh][r] = k;
    if (r < 4) bts[hh][r] = sigm(bt);
    __syncthreads();
    float mq = -1e30f, mk = -1e30f;
#pragma unroll
    for (int j = 0; j < 16; ++j) { mq = fmaxf(mq, qv[hh][j]); mk = fmaxf(mk, kv[hh][j]); }
    float sq = 0.f, sk = 0.f;
#pragma unroll
    for (int j = 0; j < 16; ++j) { sq += __expf(qv[hh][j] - mq); sk += __expf(kv[hh][j] - mk); }
    const float qsr = __expf(q - mq) / sq;
    const float ksr = __expf(k - mk) / sk;
    qsv[hh][r] = qsr; ksv[hh][r] = ksr;
    __syncthreads();
    float ay = 0.f, vyk = 0.f, vqk = 0.f, vkk = 0.f, vqq = 0.f, vkq = 0.f, vbk = 0.f, vbq = 0.f;
#pragma unroll
    for (int j = 0; j < 16; ++j) {
      const float qj = qsv[hh][j], kj = ksv[hh][j];
      ay  += wy[j]  * qj; vyk += wy[j]  * kj;
      vqq += wq[j]  * qj; vqk += wq[j]  * kj;
      vkq += wk[j]  * qj; vkk += wk[j]  * kj;
      vbq += wbr[j] * qj; vbk += wbr[j] * kj;
    }
    ayv[hh][r] = ay;
    __syncthreads();
    float ma = -1e30f;
#pragma unroll
    for (int j = 0; j < 16; ++j) ma = fmaxf(ma, ayv[hh][j]);
    float sa = 0.f;
#pragma unroll
    for (int j = 0; j < 16; ++j) sa += __expf(ayv[hh][j] - ma);
    const float vyq = __expf(ay - ma) / sa;
    const float b0 = bts[hh][0], b1v = bts[hh][1], b2v = bts[hh][2], b3v = bts[hh][3];
    const float cy = b0 * (vyq - vyk), cq = b1v * (vqq - vqk);
    const float ck = b2v * (vkq - vkk), cb = b3v * (vbq - vbk);
#pragma unroll
    for (int j = 0; j < 16; ++j) {
      const float kj = ksv[hh][j];
      wy[j] += cy * kj; wq[j] += cq * kj; wk[j] += ck * kj; wbr[j] += cb * kj;
    }
    // LN over full 256-dim y (all heads)
    float rs = y, rq = y * y;
#pragma unroll
    for (int o = 32; o > 0; o >>= 1) { rs += __shfl_down(rs, o, 64); rq += __shfl_down(rq, o, 64); }
    if ((t & 63) == 0) { sum4[t >> 6] = rs; sq4[t >> 6] = rq; }
    __syncthreads();
    const float m = (sum4[0] + sum4[1] + sum4[2] + sum4[3]) * (1.f / 256.f);
    const float var = (sq4[0] + sq4[1] + sq4[2] + sq4[3]) * (1.f / 256.f) - m * m;
    h[base + t] = (y - m) * rsqrtf(var + LEPS) * gg + bb;
  }
}

// ---------------- channel mixer: LN(D) + 256->128->256 FFN ----------------
// grid = S*B*P = 2048 blocks, 256 threads
__global__ __launch_bounds__(256) void k_ch_mixer(
    float* __restrict__ h, const float* __restrict__ g, const float* __restrict__ bta,
    const float* __restrict__ W1, const float* __restrict__ b1,
    const float* __restrict__ W2, const float* __restrict__ b2) {
  const int row = blockIdx.x;
  const int t = threadIdx.x;
  __shared__ float lnv[256], hid[128];
  __shared__ float sum4[4], sq4[4];
  const size_t base = (size_t)row * cD;
  const float v = h[base + t];
  float rs = v, rq = v * v;
#pragma unroll
  for (int o = 32; o > 0; o >>= 1) { rs += __shfl_down(rs, o, 64); rq += __shfl_down(rq, o, 64); }
  if ((t & 63) == 0) { sum4[t >> 6] = rs; sq4[t >> 6] = rq; }
  __syncthreads();
  const float m = (sum4[0] + sum4[1] + sum4[2] + sum4[3]) * (1.f / 256.f);
  const float var = (sq4[0] + sq4[1] + sq4[2] + sq4[3]) * (1.f / 256.f) - m * m;
  lnv[t] = (v - m) * rsqrtf(var + LEPS) * g[t] + bta[t];
  __syncthreads();
  if (t < cDFT) {
    float acc = b1[t];
    for (int j = 0; j < cD; ++j) acc += lnv[j] * W1[(size_t)j * cDFT + t];
    hid[t] = gelu_t(acc);
  }
  __syncthreads();
  float acc2 = b2[t];
  for (int e = 0; e < cDFT; ++e) acc2 += hid[e] * W2[(size_t)e * cD + t];
  h[base + t] = v + acc2;
}

// ---------------- final LN + mean over patches -----------------------------
// grid = S*B blocks, 256 threads
__global__ __launch_bounds__(256) void k_fln_mean(
    const float* __restrict__ h, const float* __restrict__ gg, const float* __restrict__ bbv,
    float* __restrict__ o) {
  const int sb = blockIdx.x;
  const int t = threadIdx.x;
  __shared__ float sum4[4], sq4[4];
  const float gv = gg[t], bv = bbv[t];
  float acc = 0.f;
  for (int p = 0; p < cP; ++p) {
    const size_t base = ((size_t)sb * cP + p) * cD;
    const float v = h[base + t];
    float rs = v, rq = v * v;
#pragma unroll
    for (int o2 = 32; o2 > 0; o2 >>= 1) { rs += __shfl_down(rs, o2, 64); rq += __shfl_down(rq, o2, 64); }
    if ((t & 63) == 0) { sum4[t >> 6] = rs; sq4[t >> 6] = rq; }
    __syncthreads();
    const float m = (sum4[0] + sum4[1] + sum4[2] + sum4[3]) * (1.f / 256.f);
    const float var = (sq4[0] + sq4[1] + sq4[2] + sq4[3]) * (1.f / 256.f) - m * m;
    acc += (v - m) * rsqrtf(var + LEPS) * gv + bv;
    __syncthreads();
  }
  o[(size_t)sb * cD + t] = acc * (1.f / 16.f);
}

// ---------------- output SRWM (batch=B) + final projection ----------------
// grid = B = 8 blocks
__global__ __launch_bounds__(256) void k_out_srwm(
    const float* __restrict__ gin, float* __restrict__ outp,
    const float* __restrict__ Wy0, const float* __restrict__ Wq0,
    const float* __restrict__ Wk0, const float* __restrict__ wb0,
    const float* __restrict__ lng, const float* __restrict__ lnb,
    const float* __restrict__ outW, const float* __restrict__ outb) {
  const int t = threadIdx.x;
  const int hh = t >> 4, r = t & 15;
  const int b = blockIdx.x;
  float wy[16], wq[16], wk[16], wbr[16];
#pragma unroll
  for (int j = 0; j < 16; ++j) {
    wy[j]  = Wy0[(hh * 16 + r) * 16 + j];
    wq[j]  = Wq0[(hh * 16 + r) * 16 + j];
    wk[j]  = Wk0[(hh * 16 + r) * 16 + j];
    wbr[j] = wb0[(hh * 4 + (r & 3)) * 16 + j];
  }
  __shared__ float xs[256], lnv[256];
  __shared__ float qv[16][16], kv[16][16], qsv[16][16], ksv[16][16], ayv[16][16];
  __shared__ float bts[16][4];
  __shared__ float sum4[4], sq4[4];
  const float gg = lng[t], bb = lnb[t];
  for (int s = 0; s < cS; ++s) {
    const size_t base = (size_t)(s * cB + b) * cD;
    xs[t] = gin[base + t];
    __syncthreads();
    float y = 0.f, q = 0.f, k = 0.f, bt = 0.f;
#pragma unroll
    for (int j = 0; j < 16; ++j) {
      const float xv = xs[hh * 16 + j];
      y += wy[j] * xv; q += wq[j] * xv; k += wk[j] * xv; bt += wbr[j] * xv;
    }
    qv[hh][r] = q; kv[hh][r] = k;
    if (r < 4) bts[hh][r] = sigm(bt);
    __syncthreads();
    float mq = -1e30f, mk = -1e30f;
#pragma unroll
    for (int j = 0; j < 16; ++j) { mq = fmaxf(mq, qv[hh][j]); mk = fmaxf(mk, kv[hh][j]); }
    float sq = 0.f, sk = 0.f;
#pragma unroll
    for (int j = 0; j < 16; ++j) { sq += __expf(qv[hh][j] - mq); sk += __expf(kv[hh][j] - mk); }
    const float qsr = __expf(q - mq) / sq;
    const float ksr = __expf(k - mk) / sk;
    qsv[hh][r] = qsr; ksv[hh][r] = ksr;
    __syncthreads();
    float ay = 0.f, vyk = 0.f, vqk = 0.f, vkk = 0.f, vqq = 0.f, vkq = 0.f, vbk = 0.f, vbq = 0.f;
#pragma unroll
    for (int j = 0; j < 16; ++j) {
      const float qj = qsv[hh][j], kj = ksv[hh][j];
      ay  += wy[j]  * qj; vyk += wy[j]  * kj;
      vqq += wq[j]  * qj; vqk += wq[j]  * kj;
      vkq += wk[j]  * qj; vkk += wk[j]  * kj;
      vbq += wbr[j] * qj; vbk += wbr[j] * kj;
    }
    ayv[hh][r] = ay;
    __syncthreads();
    float ma = -1e30f;
#pragma unroll
    for (int j = 0; j < 16; ++j) ma = fmaxf(ma, ayv[hh][j]);
    float sa = 0.f;
#pragma unroll
    for (int j = 0; j < 16; ++j) sa += __expf(ayv[hh][j] - ma);
    const float vyq = __expf(ay - ma) / sa;
    const float b0 = bts[hh][0], b1v = bts[hh][1], b2v = bts[hh][2], b3v = bts[hh][3];
    const float cy = b0 * (vyq - vyk), cq = b1v * (vqq - vqk);
    const float ck = b2v * (vkq - vkk), cb = b3v * (vbq - vbk);
#pragma unroll
    for (int j = 0; j < 16; ++j) {
      const float kj = ksv[hh][j];
      wy[j] += cy * kj; wq[j] += cq * kj; wk[j] += ck * kj; wbr[j] += cb * kj;
    }
    float rs = y, rq = y * y;
#pragma unroll
    for (int o = 32; o > 0; o >>= 1) { rs += __shfl_down(rs, o, 64); rq += __shfl_down(rq, o, 64); }
    if ((t & 63) == 0) { sum4[t >> 6] = rs; sq4[t >> 6] = rq; }
    __syncthreads();
    const float m = (sum4[0] + sum4[1] + sum4[2] + sum4[3]) * (1.f / 256.f);
    const float var = (sq4[0] + sq4[1] + sq4[2] + sq4[3]) * (1.f / 256.f) - m * m;
    lnv[t] = (y - m) * rsqrtf(var + LEPS) * gg + bb;
    __syncthreads();
    if (t < cNC) {
      float a = outb[t];
      for (int dd = 0; dd < cD; ++dd) a += lnv[dd] * outW[(size_t)dd * cNC + t];
      outp[(size_t)(s * cB + b) * cNC + t] = a;
    }
    __syncthreads();
  }
}

extern "C" void kernel_launch(void* const* d_in, const int* in_sizes, int n_in,
                              void* d_out, int out_size, void* d_ws, size_t ws_size,
                              hipStream_t stream) {
  const float* x     = (const float*)d_in[0];
  const int*   fb    = (const int*)d_in[1];
  const float* inW   = (const float*)d_in[2];
  const float* inb   = (const float*)d_in[3];
  const float* tkWy  = (const float*)d_in[4];
  const float* tkWq  = (const float*)d_in[5];
  const float* tkWk  = (const float*)d_in[6];
  const float* tkwb  = (const float*)d_in[7];
  const float* tklng = (const float*)d_in[8];
  const float* tklnb = (const float*)d_in[9];
  const float* tkmg  = (const float*)d_in[10];
  const float* tkmb  = (const float*)d_in[11];
  const float* tkmW1 = (const float*)d_in[12];
  const float* tkmb1 = (const float*)d_in[13];
  const float* tkmW2 = (const float*)d_in[14];
  const float* tkmb2 = (const float*)d_in[15];
  const float* chWy  = (const float*)d_in[16];
  const float* chWq  = (const float*)d_in[17];
  const float* chWk  = (const float*)d_in[18];
  const float* chwb  = (const float*)d_in[19];
  const float* chlng = (const float*)d_in[20];
  const float* chlnb = (const float*)d_in[21];
  const float* chmg  = (const float*)d_in[22];
  const float* chmb  = (const float*)d_in[23];
  const float* chmW1 = (const float*)d_in[24];
  const float* chmb1 = (const float*)d_in[25];
  const float* chmW2 = (const float*)d_in[26];
  const float* chmb2 = (const float*)d_in[27];
  const float* flng  = (const float*)d_in[28];
  const float* flnb  = (const float*)d_in[29];
  const float* oWy   = (const float*)d_in[30];
  const float* oWq   = (const float*)d_in[31];
  const float* oWk   = (const float*)d_in[32];
  const float* owb   = (const float*)d_in[33];
  const float* olng  = (const float*)d_in[34];
  const float* olnb  = (const float*)d_in[35];
  const float* outW  = (const float*)d_in[36];
  const float* outb  = (const float*)d_in[37];

  float* h    = (float*)d_ws;                               // (S,B,P,D) fp32 = 2 MB
  float* gbuf = h + (size_t)cS * cB * cP * cD;              // (S,B,D)
  float* outp = (float*)d_out;                              // (S,B,NC) fp32

  k_embed<<<dim3(cS * cB * cP), dim3(256), 0, stream>>>(x, fb, inW, inb, h);
  for (int i = 0; i < 2; ++i) {
    k_tok_srwm<<<dim3(128), dim3(256), 0, stream>>>(
        h, tkWy + i * 256, tkWq + i * 256, tkWk + i * 256, tkwb + i * 64,
        tklng + i * 16, tklnb + i * 16);
    k_tok_mixer<<<dim3(cS * cB), dim3(256), 0, stream>>>(
        h, tkmg + i * 256, tkmb + i * 256, tkmW1 + i * 1024, tkmb1 + i * 64,
        tkmW2 + i * 1024, tkmb2 + i * 16);
    k_ch_srwm<<<dim3(cB * cP), dim3(256), 0, stream>>>(
        h, chWy + i * 4096, chWq + i * 4096, chWk + i * 4096, chwb + i * 1024,
        chlng + i * 256, chlnb + i * 256);
    k_ch_mixer<<<dim3(cS * cB * cP), dim3(256), 0, stream>>>(
        h, chmg + i * 256, chmb + i * 256, chmW1 + i * 32768, chmb1 + i * 128,
        chmW2 + i * 32768, chmb2 + i * 256);
  }
  k_fln_mean<<<dim3(cS * cB), dim3(256), 0, stream>>>(h, flng, flnb, gbuf);
  k_out_srwm<<<dim3(cB), dim3(256), 0, stream>>>(
      gbuf, outp, oWy, oWq, oWk, owb, olng, olnb, outW, outb);
}

// Round 2
// 417.171 us; speedup vs baseline: 1.0684x; 1.0684x over previous
//
#include <hip/hip_runtime.h>
#include <math.h>

// Problem constants (from reference)
constexpr int cS  = 16;   // sequence
constexpr int cB  = 8;    // batch
constexpr int cNC = 5;    // classes
constexpr int cD  = 256;  // hidden
constexpr int cH  = 16;   // heads
constexpr int cP  = 16;   // patches
constexpr int cPD = 49;   // patch dim
constexpr int cDFT = 128; // channel-mixer hidden
constexpr int cEP  = 64;  // token-mixer hidden (EF*P)
#define LEPS 1e-5f

__device__ __forceinline__ float gelu_t(float x) {
  // jax.nn.gelu approximate=True (tanh)
  float x3 = x * x * x;
  return 0.5f * x * (1.0f + tanhf(0.7978845608028654f * (x + 0.044715f * x3)));
}
__device__ __forceinline__ float sigm(float x) { return 1.0f / (1.0f + __expf(-x)); }

// ---------------- embed: patchify + one-hot concat + linear ----------------
// grid = S*B*P blocks, 256 threads (one per output d)
__global__ __launch_bounds__(256) void k_embed(const float* __restrict__ x,
                                               const int* __restrict__ fb,
                                               const float* __restrict__ inW,
                                               const float* __restrict__ inb,
                                               float* __restrict__ h) {
  const int blk = blockIdx.x;
  const int p  = blk & 15;        // patch
  const int sb = blk >> 4;        // s*B + b
  const int ph = p >> 2, pw = p & 3;
  __shared__ float sx[cPD];
  const int t = threadIdx.x;
  if (t < cPD) {
    const int p1 = t / 7, p2 = t % 7;
    sx[t] = x[(size_t)sb * 784 + (ph * 7 + p1) * 28 + (pw * 7 + p2)];
  }
  __syncthreads();
  const int cls = fb[sb];
  float acc = inb[t] + inW[(size_t)(cPD + cls) * cD + t];  // one-hot row
#pragma unroll
  for (int j = 0; j < cPD; ++j) acc += sx[j] * inW[(size_t)j * cD + t];
  h[((size_t)sb * cP + p) * cD + t] = acc;
}

// ---------------- token SRWM: features = patch axis (16), batch = B*D ------
// grid = 128 blocks; block handles 16 instances (d0..d0+15 of one b).
// thread (li, r): instance li, row r. State rows in registers.
__global__ __launch_bounds__(256) void k_tok_srwm(
    float* __restrict__ h, const float* __restrict__ Wy0, const float* __restrict__ Wq0,
    const float* __restrict__ Wk0, const float* __restrict__ wb0,
    const float* __restrict__ lng, const float* __restrict__ lnb) {
  const int t  = threadIdx.x;
  const int li = t >> 4;          // local instance (d-lane)
  const int r  = t & 15;          // row
  const int b  = blockIdx.x >> 4;
  const int d0 = (blockIdx.x & 15) << 4;
  float wy[16], wq[16], wk[16], wbr[16];
#pragma unroll
  for (int j = 0; j < 16; ++j) {
    wy[j]  = Wy0[r * 16 + j];
    wq[j]  = Wq0[r * 16 + j];
    wk[j]  = Wk0[r * 16 + j];
    wbr[j] = wb0[(r & 3) * 16 + j];
  }
  __shared__ float xs[16][16];   // [d-lane][row]
  __shared__ float qv[16][16], kv[16][16], qsv[16][16], ksv[16][16], ayv[16][16], yv[16][16];
  __shared__ float bts[16][4];
  const float gg = lng[r], bb = lnb[r];
  const int lr = t >> 4;   // cooperative load: row
  const int ld = t & 15;   // cooperative load: d-lane
  for (int s = 0; s < cS; ++s) {
    const size_t rowbase = ((size_t)(s * cB + b) * cP) * cD + d0;
    xs[ld][lr] = h[rowbase + (size_t)lr * cD + ld];     // coalesced 16-float runs
    __syncthreads();
    float y = 0.f, q = 0.f, k = 0.f, bt = 0.f;
#pragma unroll
    for (int j = 0; j < 16; ++j) {
      const float xv = xs[li][j];
      y += wy[j] * xv; q += wq[j] * xv; k += wk[j] * xv; bt += wbr[j] * xv;
    }
    yv[li][r] = y; qv[li][r] = q; kv[li][r] = k;
    if (r < 4) bts[li][r] = sigm(bt);
    __syncthreads();
    float mq = -1e30f, mk = -1e30f;
#pragma unroll
    for (int j = 0; j < 16; ++j) { mq = fmaxf(mq, qv[li][j]); mk = fmaxf(mk, kv[li][j]); }
    float sq = 0.f, sk = 0.f;
#pragma unroll
    for (int j = 0; j < 16; ++j) { sq += __expf(qv[li][j] - mq); sk += __expf(kv[li][j] - mk); }
    const float qsr = __expf(q - mq) / sq;
    const float ksr = __expf(k - mk) / sk;
    qsv[li][r] = qsr; ksv[li][r] = ksr;
    __syncthreads();
    float ay = 0.f, vyk = 0.f, vqk = 0.f, vkk = 0.f, vqq = 0.f, vkq = 0.f, vbk = 0.f, vbq = 0.f;
#pragma unroll
    for (int j = 0; j < 16; ++j) {
      const float qj = qsv[li][j], kj = ksv[li][j];
      ay  += wy[j]  * qj; vyk += wy[j]  * kj;
      vqq += wq[j]  * qj; vqk += wq[j]  * kj;
      vkq += wk[j]  * qj; vkk += wk[j]  * kj;
      vbq += wbr[j] * qj; vbk += wbr[j] * kj;
    }
    ayv[li][r] = ay;
    __syncthreads();
    float ma = -1e30f;
#pragma unroll
    for (int j = 0; j < 16; ++j) ma = fmaxf(ma, ayv[li][j]);
    float sa = 0.f;
#pragma unroll
    for (int j = 0; j < 16; ++j) sa += __expf(ayv[li][j] - ma);
    const float vyq = __expf(ay - ma) / sa;
    const float b0 = bts[li][0], b1v = bts[li][1], b2v = bts[li][2], b3v = bts[li][3];
    const float cy = b0 * (vyq - vyk), cq = b1v * (vqq - vqk);
    const float ck = b2v * (vkq - vkk), cb = b3v * (vbq - vbk);
#pragma unroll
    for (int j = 0; j < 16; ++j) {
      const float kj = ksv[li][j];
      wy[j] += cy * kj; wq[j] += cq * kj; wk[j] += ck * kj; wbr[j] += cb * kj;
    }
    // LN over the 16-dim y (per instance)
    float m = 0.f;
#pragma unroll
    for (int j = 0; j < 16; ++j) m += yv[li][j];
    m *= 0.0625f;
    float var = 0.f;
#pragma unroll
    for (int j = 0; j < 16; ++j) { const float dv = yv[li][j] - m; var += dv * dv; }
    var *= 0.0625f;
    const float outv = (y - m) * rsqrtf(var + LEPS) * gg + bb;
    qv[li][r] = outv;          // reuse qv as output staging (reads done pre-sync)
    __syncthreads();
    h[rowbase + (size_t)lr * cD + ld] = qv[ld][lr];     // coalesced store
  }
}

// ---------------- token mixer: LN(D) then FFN over patch axis --------------
// grid = S*B blocks, 256 threads (one per d)
__global__ __launch_bounds__(256) void k_tok_mixer(
    float* __restrict__ h, const float* __restrict__ g, const float* __restrict__ bta,
    const float* __restrict__ W1, const float* __restrict__ b1,
    const float* __restrict__ W2, const float* __restrict__ b2) {
  const int sb = blockIdx.x;
  const int t = threadIdx.x;
  __shared__ float tile[16][256];
  __shared__ float W1s[16 * 64], W2s[64 * 16];
  __shared__ float mean_[16], rstd_[16];
  __shared__ float red[16][17], red2[16][17];
  const size_t base = (size_t)sb * cP * cD;
#pragma unroll
  for (int p = 0; p < 16; ++p) tile[p][t] = h[base + p * 256 + t];
  W1s[t] = W1[t]; W1s[t + 256] = W1[t + 256]; W1s[t + 512] = W1[t + 512]; W1s[t + 768] = W1[t + 768];
  W2s[t] = W2[t]; W2s[t + 256] = W2[t + 256]; W2s[t + 512] = W2[t + 512]; W2s[t + 768] = W2[t + 768];
  __syncthreads();
  // LN stats: 16 threads per row p
  const int p = t >> 4, l = t & 15;
  float ps = 0.f, ps2 = 0.f;
#pragma unroll
  for (int k = 0; k < 16; ++k) { const float v = tile[p][l + 16 * k]; ps += v; ps2 += v * v; }
  red[p][l] = ps; red2[p][l] = ps2;
  __syncthreads();
  if (t < 16) {
    float sm = 0.f, s2 = 0.f;
#pragma unroll
    for (int k = 0; k < 16; ++k) { sm += red[t][k]; s2 += red2[t][k]; }
    const float m = sm * (1.f / 256.f);
    mean_[t] = m;
    rstd_[t] = rsqrtf(s2 * (1.f / 256.f) - m * m + LEPS);
  }
  __syncthreads();
  const float gd = g[t], bd = bta[t];
  float v[16], out[16];
#pragma unroll
  for (int pp = 0; pp < 16; ++pp) {
    v[pp] = (tile[pp][t] - mean_[pp]) * rstd_[pp] * gd + bd;
    out[pp] = b2[pp];
  }
  for (int e = 0; e < cEP; ++e) {
    float acc = b1[e];
#pragma unroll
    for (int pp = 0; pp < 16; ++pp) acc += v[pp] * W1s[pp * 64 + e];
    const float ge = gelu_t(acc);
#pragma unroll
    for (int pp = 0; pp < 16; ++pp) out[pp] += ge * W2s[e * 16 + pp];
  }
#pragma unroll
  for (int pp = 0; pp < 16; ++pp) h[base + pp * 256 + t] = tile[pp][t] + out[pp];
}

// ---------------- channel SRWM: 16 heads of dh=16, batch = B*P -------------
// grid = B*P = 128 blocks; thread (hh, r). LN couples all heads (dim 256).
__global__ __launch_bounds__(256) void k_ch_srwm(
    float* __restrict__ h, const float* __restrict__ Wy0, const float* __restrict__ Wq0,
    const float* __restrict__ Wk0, const float* __restrict__ wb0,
    const float* __restrict__ lng, const float* __restrict__ lnb) {
  const int t = threadIdx.x;
  const int hh = t >> 4, r = t & 15;
  const int bp = blockIdx.x;
  float wy[16], wq[16], wk[16], wbr[16];
#pragma unroll
  for (int j = 0; j < 16; ++j) {
    wy[j]  = Wy0[(hh * 16 + r) * 16 + j];
    wq[j]  = Wq0[(hh * 16 + r) * 16 + j];
    wk[j]  = Wk0[(hh * 16 + r) * 16 + j];
    wbr[j] = wb0[(hh * 4 + (r & 3)) * 16 + j];
  }
  __shared__ float xs[256];
  __shared__ float qv[16][16], kv[16][16], qsv[16][16], ksv[16][16], ayv[16][16];
  __shared__ float bts[16][4];
  __shared__ float sum4[4], sq4[4];
  const float gg = lng[t], bb = lnb[t];
  for (int s = 0; s < cS; ++s) {
    const size_t base = (size_t)(s * cB * cP + bp) * cD;
    xs[t] = h[base + t];
    __syncthreads();
    float y = 0.f, q = 0.f, k = 0.f, bt = 0.f;
#pragma unroll
    for (int j = 0; j < 16; ++j) {
      const float xv = xs[hh * 16 + j];
      y += wy[j] * xv; q += wq[j] * xv; k += wk[j] * xv; bt += wbr[j] * xv;
    }
    qv[hh][r] = q; kv[hh][r] = k;
    if (r < 4) bts[hh][r] = sigm(bt);
    __syncthreads();
    float mq = -1e30f, mk = -1e30f;
#pragma unroll
    for (int j = 0; j < 16; ++j) { mq = fmaxf(mq, qv[hh][j]); mk = fmaxf(mk, kv[hh][j]); }
    float sq = 0.f, sk = 0.f;
#pragma unroll
    for (int j = 0; j < 16; ++j) { sq += __expf(qv[hh][j] - mq); sk += __expf(kv[hh][j] - mk); }
    const float qsr = __expf(q - mq) / sq;
    const float ksr = __expf(k - mk) / sk;
    qsv[hh][r] = qsr; ksv[hh][r] = ksr;
    __syncthreads();
    float ay = 0.f, vyk = 0.f, vqk = 0.f, vkk = 0.f, vqq = 0.f, vkq = 0.f, vbk = 0.f, vbq = 0.f;
#pragma unroll
    for (int j = 0; j < 16; ++j) {
      const float qj = qsv[hh][j], kj = ksv[hh][j];
      ay  += wy[j]  * qj; vyk += wy[j]  * kj;
      vqq += wq[j]  * qj; vqk += wq[j]  * kj;
      vkq += wk[j]  * qj; vkk += wk[j]  * kj;
      vbq += wbr[j] * qj; vbk += wbr[j] * kj;
    }
    ayv[hh][r] = ay;
    __syncthreads();
    float ma = -1e30f;
#pragma unroll
    for (int j = 0; j < 16; ++j) ma = fmaxf(ma, ayv[hh][j]);
    float sa = 0.f;
#pragma unroll
    for (int j = 0; j < 16; ++j) sa += __expf(ayv[hh][j] - ma);
    const float vyq = __expf(ay - ma) / sa;
    const float b0 = bts[hh][0], b1v = bts[hh][1], b2v = bts[hh][2], b3v = bts[hh][3];
    const float cy = b0 * (vyq - vyk), cq = b1v * (vqq - vqk);
    const float ck = b2v * (vkq - vkk), cb = b3v * (vbq - vbk);
#pragma unroll
    for (int j = 0; j < 16; ++j) {
      const float kj = ksv[hh][j];
      wy[j] += cy * kj; wq[j] += cq * kj; wk[j] += ck * kj; wbr[j] += cb * kj;
    }
    // LN over full 256-dim y (all heads)
    float rs = y, rq = y * y;
#pragma unroll
    for (int o = 32; o > 0; o >>= 1) { rs += __shfl_down(rs, o, 64); rq += __shfl_down(rq, o, 64); }
    if ((t & 63) == 0) { sum4[t >> 6] = rs; sq4[t >> 6] = rq; }
    __syncthreads();
    const float m = (sum4[0] + sum4[1] + sum4[2] + sum4[3]) * (1.f / 256.f);
    const float var = (sq4[0] + sq4[1] + sq4[2] + sq4[3]) * (1.f / 256.f) - m * m;
    h[base + t] = (y - m) * rsqrtf(var + LEPS) * gg + bb;
  }
}

// ---------------- channel mixer: LN(D) + 256->128->256 FFN ----------------
// grid = S*B*P = 2048 blocks, 256 threads
__global__ __launch_bounds__(256) void k_ch_mixer(
    float* __restrict__ h, const float* __restrict__ g, const float* __restrict__ bta,
    const float* __restrict__ W1, const float* __restrict__ b1,
    const float* __restrict__ W2, const float* __restrict__ b2) {
  const int row = blockIdx.x;
  const int t = threadIdx.x;
  __shared__ float lnv[256], hid[128];
  __shared__ float sum4[4], sq4[4];
  const size_t base = (size_t)row * cD;
  const float v = h[base + t];
  float rs = v, rq = v * v;
#pragma unroll
  for (int o = 32; o > 0; o >>= 1) { rs += __shfl_down(rs, o, 64); rq += __shfl_down(rq, o, 64); }
  if ((t & 63) == 0) { sum4[t >> 6] = rs; sq4[t >> 6] = rq; }
  __syncthreads();
  const float m = (sum4[0] + sum4[1] + sum4[2] + sum4[3]) * (1.f / 256.f);
  const float var = (sq4[0] + sq4[1] + sq4[2] + sq4[3]) * (1.f / 256.f) - m * m;
  lnv[t] = (v - m) * rsqrtf(var + LEPS) * g[t] + bta[t];
  __syncthreads();
  if (t < cDFT) {
    float acc = b1[t];
    for (int j = 0; j < cD; ++j) acc += lnv[j] * W1[(size_t)j * cDFT + t];
    hid[t] = gelu_t(acc);
  }
  __syncthreads();
  float acc2 = b2[t];
  for (int e = 0; e < cDFT; ++e) acc2 += hid[e] * W2[(size_t)e * cD + t];
  h[base + t] = v + acc2;
}

// ---------------- final LN + mean over patches -----------------------------
// grid = S*B blocks, 256 threads
__global__ __launch_bounds__(256) void k_fln_mean(
    const float* __restrict__ h, const float* __restrict__ gg, const float* __restrict__ bbv,
    float* __restrict__ o) {
  const int sb = blockIdx.x;
  const int t = threadIdx.x;
  __shared__ float sum4[4], sq4[4];
  const float gv = gg[t], bv = bbv[t];
  float acc = 0.f;
  for (int p = 0; p < cP; ++p) {
    const size_t base = ((size_t)sb * cP + p) * cD;
    const float v = h[base + t];
    float rs = v, rq = v * v;
#pragma unroll
    for (int o2 = 32; o2 > 0; o2 >>= 1) { rs += __shfl_down(rs, o2, 64); rq += __shfl_down(rq, o2, 64); }
    if ((t & 63) == 0) { sum4[t >> 6] = rs; sq4[t >> 6] = rq; }
    __syncthreads();
    const float m = (sum4[0] + sum4[1] + sum4[2] + sum4[3]) * (1.f / 256.f);
    const float var = (sq4[0] + sq4[1] + sq4[2] + sq4[3]) * (1.f / 256.f) - m * m;
    acc += (v - m) * rsqrtf(var + LEPS) * gv + bv;
    __syncthreads();
  }
  o[(size_t)sb * cD + t] = acc * (1.f / 16.f);
}

// ---------------- output SRWM (batch=B) + final projection ----------------
// grid = B = 8 blocks
// R1 fix: projection parallelized over all 256 threads (was 5 threads x
// 256-iter serial loop = the 75us stall). outW row hoisted to registers.
__global__ __launch_bounds__(256) void k_out_srwm(
    const float* __restrict__ gin, float* __restrict__ outp,
    const float* __restrict__ Wy0, const float* __restrict__ Wq0,
    const float* __restrict__ Wk0, const float* __restrict__ wb0,
    const float* __restrict__ lng, const float* __restrict__ lnb,
    const float* __restrict__ outW, const float* __restrict__ outb) {
  const int t = threadIdx.x;
  const int hh = t >> 4, r = t & 15;
  const int b = blockIdx.x;
  float wy[16], wq[16], wk[16], wbr[16];
#pragma unroll
  for (int j = 0; j < 16; ++j) {
    wy[j]  = Wy0[(hh * 16 + r) * 16 + j];
    wq[j]  = Wq0[(hh * 16 + r) * 16 + j];
    wk[j]  = Wk0[(hh * 16 + r) * 16 + j];
    wbr[j] = wb0[(hh * 4 + (r & 3)) * 16 + j];
  }
  // hoist this thread's outW row (constant across steps)
  float wrow[cNC];
#pragma unroll
  for (int c = 0; c < cNC; ++c) wrow[c] = outW[(size_t)t * cNC + c];
  __shared__ float xs[256];
  __shared__ float qv[16][16], kv[16][16], qsv[16][16], ksv[16][16], ayv[16][16];
  __shared__ float bts[16][4];
  __shared__ float sum4[4], sq4[4];
  __shared__ float red[4][cNC];
  const float gg = lng[t], bb = lnb[t];
  for (int s = 0; s < cS; ++s) {
    const size_t base = (size_t)(s * cB + b) * cD;
    xs[t] = gin[base + t];
    __syncthreads();
    float y = 0.f, q = 0.f, k = 0.f, bt = 0.f;
#pragma unroll
    for (int j = 0; j < 16; ++j) {
      const float xv = xs[hh * 16 + j];
      y += wy[j] * xv; q += wq[j] * xv; k += wk[j] * xv; bt += wbr[j] * xv;
    }
    qv[hh][r] = q; kv[hh][r] = k;
    if (r < 4) bts[hh][r] = sigm(bt);
    __syncthreads();
    float mq = -1e30f, mk = -1e30f;
#pragma unroll
    for (int j = 0; j < 16; ++j) { mq = fmaxf(mq, qv[hh][j]); mk = fmaxf(mk, kv[hh][j]); }
    float sq = 0.f, sk = 0.f;
#pragma unroll
    for (int j = 0; j < 16; ++j) { sq += __expf(qv[hh][j] - mq); sk += __expf(kv[hh][j] - mk); }
    const float qsr = __expf(q - mq) / sq;
    const float ksr = __expf(k - mk) / sk;
    qsv[hh][r] = qsr; ksv[hh][r] = ksr;
    __syncthreads();
    float ay = 0.f, vyk = 0.f, vqk = 0.f, vkk = 0.f, vqq = 0.f, vkq = 0.f, vbk = 0.f, vbq = 0.f;
#pragma unroll
    for (int j = 0; j < 16; ++j) {
      const float qj = qsv[hh][j], kj = ksv[hh][j];
      ay  += wy[j]  * qj; vyk += wy[j]  * kj;
      vqq += wq[j]  * qj; vqk += wq[j]  * kj;
      vkq += wk[j]  * qj; vkk += wk[j]  * kj;
      vbq += wbr[j] * qj; vbk += wbr[j] * kj;
    }
    ayv[hh][r] = ay;
    __syncthreads();
    float ma = -1e30f;
#pragma unroll
    for (int j = 0; j < 16; ++j) ma = fmaxf(ma, ayv[hh][j]);
    float sa = 0.f;
#pragma unroll
    for (int j = 0; j < 16; ++j) sa += __expf(ayv[hh][j] - ma);
    const float vyq = __expf(ay - ma) / sa;
    const float b0 = bts[hh][0], b1v = bts[hh][1], b2v = bts[hh][2], b3v = bts[hh][3];
    const float cy = b0 * (vyq - vyk), cq = b1v * (vqq - vqk);
    const float ck = b2v * (vkq - vkk), cb = b3v * (vbq - vbk);
#pragma unroll
    for (int j = 0; j < 16; ++j) {
      const float kj = ksv[hh][j];
      wy[j] += cy * kj; wq[j] += cq * kj; wk[j] += ck * kj; wbr[j] += cb * kj;
    }
    float rs = y, rq = y * y;
#pragma unroll
    for (int o = 32; o > 0; o >>= 1) { rs += __shfl_down(rs, o, 64); rq += __shfl_down(rq, o, 64); }
    if ((t & 63) == 0) { sum4[t >> 6] = rs; sq4[t >> 6] = rq; }
    __syncthreads();
    const float m = (sum4[0] + sum4[1] + sum4[2] + sum4[3]) * (1.f / 256.f);
    const float var = (sq4[0] + sq4[1] + sq4[2] + sq4[3]) * (1.f / 256.f) - m * m;
    const float lnt = (y - m) * rsqrtf(var + LEPS) * gg + bb;
    // projection: all 256 threads contribute lnt * wrow[c]; reduce.
    float pc[cNC];
#pragma unroll
    for (int c = 0; c < cNC; ++c) {
      float pv = lnt * wrow[c];
#pragma unroll
      for (int o = 32; o > 0; o >>= 1) pv += __shfl_down(pv, o, 64);
      pc[c] = pv;
    }
    if ((t & 63) == 0) {
#pragma unroll
      for (int c = 0; c < cNC; ++c) red[t >> 6][c] = pc[c];
    }
    __syncthreads();
    if (t < cNC) {
      outp[(size_t)(s * cB + b) * cNC + t] =
          outb[t] + red[0][t] + red[1][t] + red[2][t] + red[3][t];
    }
    __syncthreads();
  }
}

extern "C" void kernel_launch(void* const* d_in, const int* in_sizes, int n_in,
                              void* d_out, int out_size, void* d_ws, size_t ws_size,
                              hipStream_t stream) {
  const float* x     = (const float*)d_in[0];
  const int*   fb    = (const int*)d_in[1];
  const float* inW   = (const float*)d_in[2];
  const float* inb   = (const float*)d_in[3];
  const float* tkWy  = (const float*)d_in[4];
  const float* tkWq  = (const float*)d_in[5];
  const float* tkWk  = (const float*)d_in[6];
  const float* tkwb  = (const float*)d_in[7];
  const float* tklng = (const float*)d_in[8];
  const float* tklnb = (const float*)d_in[9];
  const float* tkmg  = (const float*)d_in[10];
  const float* tkmb  = (const float*)d_in[11];
  const float* tkmW1 = (const float*)d_in[12];
  const float* tkmb1 = (const float*)d_in[13];
  const float* tkmW2 = (const float*)d_in[14];
  const float* tkmb2 = (const float*)d_in[15];
  const float* chWy  = (const float*)d_in[16];
  const float* chWq  = (const float*)d_in[17];
  const float* chWk  = (const float*)d_in[18];
  const float* chwb  = (const float*)d_in[19];
  const float* chlng = (const float*)d_in[20];
  const float* chlnb = (const float*)d_in[21];
  const float* chmg  = (const float*)d_in[22];
  const float* chmb  = (const float*)d_in[23];
  const float* chmW1 = (const float*)d_in[24];
  const float* chmb1 = (const float*)d_in[25];
  const float* chmW2 = (const float*)d_in[26];
  const float* chmb2 = (const float*)d_in[27];
  const float* flng  = (const float*)d_in[28];
  const float* flnb  = (const float*)d_in[29];
  const float* oWy   = (const float*)d_in[30];
  const float* oWq   = (const float*)d_in[31];
  const float* oWk   = (const float*)d_in[32];
  const float* owb   = (const float*)d_in[33];
  const float* olng  = (const float*)d_in[34];
  const float* olnb  = (const float*)d_in[35];
  const float* outW  = (const float*)d_in[36];
  const float* outb  = (const float*)d_in[37];

  float* h    = (float*)d_ws;                               // (S,B,P,D) fp32 = 2 MB
  float* gbuf = h + (size_t)cS * cB * cP * cD;              // (S,B,D)
  float* outp = (float*)d_out;                              // (S,B,NC) fp32

  k_embed<<<dim3(cS * cB * cP), dim3(256), 0, stream>>>(x, fb, inW, inb, h);
  for (int i = 0; i < 2; ++i) {
    k_tok_srwm<<<dim3(128), dim3(256), 0, stream>>>(
        h, tkWy + i * 256, tkWq + i * 256, tkWk + i * 256, tkwb + i * 64,
        tklng + i * 16, tklnb + i * 16);
    k_tok_mixer<<<dim3(cS * cB), dim3(256), 0, stream>>>(
        h, tkmg + i * 256, tkmb + i * 256, tkmW1 + i * 1024, tkmb1 + i * 64,
        tkmW2 + i * 1024, tkmb2 + i * 16);
    k_ch_srwm<<<dim3(cB * cP), dim3(256), 0, stream>>>(
        h, chWy + i * 4096, chWq + i * 4096, chWk + i * 4096, chwb + i * 1024,
        chlng + i * 256, chlnb + i * 256);
    k_ch_mixer<<<dim3(cS * cB * cP), dim3(256), 0, stream>>>(
        h, chmg + i * 256, chmb + i * 256, chmW1 + i * 32768, chmb1 + i * 128,
        chmW2 + i * 32768, chmb2 + i * 256);
  }
  k_fln_mean<<<dim3(cS * cB), dim3(256), 0, stream>>>(h, flng, flnb, gbuf);
  k_out_srwm<<<dim3(cB), dim3(256), 0, stream>>>(
      gbuf, outp, oWy, oWq, oWk, owb, olng, olnb, outW, outb);
}